// Round 10
// baseline (418.120 us; speedup 1.0000x reference)
//
#include <hip/hip_runtime.h>
#include <hip/hip_bf16.h>

#define T_ 4
#define B_ 4
#define N_ 16384
#define KALL_ 4
#define F_ 16384
#define ORD_ 3
#define DIN_ 4
#define H_ 64
#define H3_ 192
#define DE_ 4
#define STR 72     // padded bf16 leading-dim for MFMA A/B LDS tiles
#define NE_ 49152  // F*ORD edges

typedef __attribute__((ext_vector_type(8))) short s16x8;
typedef __attribute__((ext_vector_type(4))) float f32x4;
typedef unsigned long long u64;

static __device__ __forceinline__ float b2f(unsigned short u) {
  union { unsigned u; float f; } x; x.u = ((unsigned)u) << 16; return x.f;
}
static __device__ __forceinline__ unsigned short f2b(float f) {
  __hip_bfloat16 h = __float2bfloat16(f);  // RNE
  union { __hip_bfloat16 h; unsigned short u; } x; x.h = h; return x.u;
}
static __device__ __forceinline__ float fast_sigmoid(float v) {
  return __fdividef(1.f, 1.f + __expf(-v));
}
static __device__ __forceinline__ float fast_tanh(float v) {
  float e = __expf(2.f * v);
  return __fdividef(e - 1.f, e + 1.f);
}
// XOR swizzle on the k-index of a [row][k] bf16 tile with leading dim STR:
// spreads bank index for both staging writes and frag reads; preserves
// 8-element (16 B) block alignment since the mask is a multiple of 8.
#define SWZ(row, k) ((k) ^ (((row) & 7) << 3))

// dones encoding sniffer (unchanged — proven in R7-R9)
static __device__ __forceinline__ bool decode_done(const int* __restrict__ dn, int tb) {
  bool word = true;
#pragma unroll
  for (int i = 0; i < 16; ++i) {
    int v = dn[i];
    if (v != 0 && v != 1 && v != 0x3F800000) word = false;
  }
  if (word) return dn[tb] != 0;
  return ((const unsigned char*)dn)[tb] != 0;
}

// ---------------------------------------------------------------------------
// CSR build (unchanged from R9)
// ---------------------------------------------------------------------------
__global__ __launch_bounds__(256) void k_csr_count(
    const int* __restrict__ idx, int* __restrict__ cnt) {
  int e = blockIdx.x * 256 + threadIdx.x;
  if (e < NE_) atomicAdd(&cnt[idx[e]], 1);
}
__global__ __launch_bounds__(256) void k_csr_scan(
    const int* __restrict__ cnt, int* __restrict__ offs, int* __restrict__ cursor) {
  __shared__ int part[256];
  __shared__ int base[256];
  int t = threadIdx.x;
  int s = 0;
  for (int j = 0; j < 64; ++j) s += cnt[t * 64 + j];
  part[t] = s;
  __syncthreads();
  if (t == 0) {
    int run = 0;
    for (int i = 0; i < 256; ++i) { base[i] = run; run += part[i]; }
  }
  __syncthreads();
  int run = base[t];
  for (int j = 0; j < 64; ++j) {
    offs[t * 64 + j] = run;
    cursor[t * 64 + j] = run;
    run += cnt[t * 64 + j];
  }
  if (t == 255) offs[N_] = run;
}
__global__ __launch_bounds__(256) void k_csr_fill(
    const int* __restrict__ idx, int* __restrict__ cursor, int* __restrict__ elist) {
  int e = blockIdx.x * 256 + threadIdx.x;
  if (e < NE_) {
    int pos = atomicAdd(&cursor[idx[e]], 1);
    elist[pos] = e;
  }
}

// ---------------------------------------------------------------------------
// Kernel 1: GRU v2. LDS 37.9 KB (bf16-only carry) -> 4 blocks/CU; fast
// sigmoid/tanh; XOR-swizzled whT/carry banks.
// ---------------------------------------------------------------------------
__global__ __launch_bounds__(256, 4) void k_gru(
    const float* __restrict__ h0,
    const float* __restrict__ x,
    const int* __restrict__ dones,
    const float* __restrict__ Wi,
    const float* __restrict__ bi,
    const float* __restrict__ Wh,
    const float* __restrict__ bhn,
    unsigned short* __restrict__ hs,     // [T*B,N,H] bf16
    float* __restrict__ hfin)            // [B,N,H] f32
{
  __shared__ short whT[H3_ * STR];   // whT[c][swz k] = Wh[k][c] (B-operand)
  __shared__ short carry[H_ * STR];  // carry[r][swz k] bf16 (A-operand + state)
  __shared__ float xt[256];

  const int tid = threadIdx.x;
  const int lane = tid & 63;
  const int w = tid >> 6;
  const int c15 = lane & 15;
  const int hi4 = lane >> 4;
  const int bid = blockIdx.x;
  const int b = bid >> 8;
  const int nbase = (bid & 255) * 64;

  for (int i = tid; i < H_ * H3_; i += 256) {
    int k = i / H3_;
    int c = i - k * H3_;
    whT[c * STR + SWZ(c, k)] = (short)f2b(Wh[i]);
  }
  for (int i = tid; i < H_ * H_; i += 256) {
    int r = i >> 6, k = i & 63;
    carry[r * STR + SWZ(r, k)] = (short)f2b(h0[(b * N_ + nbase + r) * H_ + k]);
  }
  bool rst[T_];
#pragma unroll
  for (int t = 0; t < T_; ++t) rst[t] = decode_done(dones, t * B_ + b);

  float wir[3][4][4], bir[3][4], bhnr[4];
#pragma unroll
  for (int cg = 0; cg < 4; ++cg) {
    int hc = 16 * cg + c15;
    bhnr[cg] = bhn[hc];
#pragma unroll
    for (int g = 0; g < 3; ++g) {
      bir[g][cg] = bi[g * 64 + hc];
#pragma unroll
      for (int kk = 0; kk < 4; ++kk)
        wir[g][cg][kk] = Wi[kk * H3_ + g * 64 + hc];
    }
  }
  __syncthreads();

  for (int t = 0; t < T_; ++t) {
    xt[tid] = x[((t * B_ + b) * N_ + nbase + (tid >> 2)) * DIN_ + (tid & 3)];
    if (rst[t]) {
      for (int i = tid; i < H_ * STR; i += 256) carry[i] = 0;
    }
    __syncthreads();

    f32x4 acc[12];
#pragma unroll
    for (int ct = 0; ct < 12; ++ct) acc[ct] = (f32x4){0.f, 0.f, 0.f, 0.f};
    const int rowA = 16 * w + c15;
#pragma unroll
    for (int ks = 0; ks < 2; ++ks) {
      const int kb = ks * 32 + hi4 * 8;
      s16x8 af = *(const s16x8*)&carry[rowA * STR + SWZ(rowA, kb)];
#pragma unroll
      for (int ct = 0; ct < 12; ++ct) {
        const int colB = 16 * ct + c15;
        s16x8 bfr = *(const s16x8*)&whT[colB * STR + SWZ(colB, kb)];
        acc[ct] = __builtin_amdgcn_mfma_f32_16x16x32_bf16(af, bfr, acc[ct], 0, 0, 0);
      }
    }
#pragma unroll
    for (int r = 0; r < 4; ++r) {
      const int row = 16 * w + hi4 * 4 + r;
      const int node = nbase + row;
      const float x0 = xt[row * 4 + 0], x1 = xt[row * 4 + 1],
                  x2 = xt[row * 4 + 2], x3 = xt[row * 4 + 3];
#pragma unroll
      for (int cg = 0; cg < 4; ++cg) {
        const int hc = 16 * cg + c15;
        float gr = bir[0][cg] + x0 * wir[0][cg][0] + x1 * wir[0][cg][1]
                 + x2 * wir[0][cg][2] + x3 * wir[0][cg][3] + acc[cg][r];
        float gz = bir[1][cg] + x0 * wir[1][cg][0] + x1 * wir[1][cg][1]
                 + x2 * wir[1][cg][2] + x3 * wir[1][cg][3] + acc[4 + cg][r];
        float gn = bir[2][cg] + x0 * wir[2][cg][0] + x1 * wir[2][cg][1]
                 + x2 * wir[2][cg][2] + x3 * wir[2][cg][3];
        float rg = fast_sigmoid(gr);
        float zg = fast_sigmoid(gz);
        float cold = b2f((unsigned short)carry[row * STR + SWZ(row, hc)]);
        float ng = fast_tanh(gn + rg * (acc[8 + cg][r] + bhnr[cg]));
        float nc = (1.f - zg) * ng + zg * cold;
        hs[((t * B_ + b) * N_ + node) * H_ + hc] = f2b(nc);
        if (t == T_ - 1) hfin[(b * N_ + node) * H_ + hc] = nc;
        carry[row * STR + SWZ(row, hc)] = (short)f2b(nc);
      }
    }
    __syncthreads();
  }
}

// ---------------------------------------------------------------------------
// Kernel 2: fused factor attention v4. Grid 2048 = 1024 chunks x 2 subs;
// block handles 4 (t,b) slices of one half. No atomics (a_edge stream-out).
// ---------------------------------------------------------------------------
__global__ __launch_bounds__(256, 3) void k_attn(
    const int tb0,
    const unsigned short* __restrict__ hs,    // [T*B,N,H] bf16
    const int* __restrict__ indices,
    const float* __restrict__ Wq, const float* __restrict__ bq,
    const float* __restrict__ Wk, const float* __restrict__ bk,
    const float* __restrict__ Wv, const float* __restrict__ bv,
    const float* __restrict__ Wo, const float* __restrict__ bo,
    unsigned short* __restrict__ a_edge)      // [8,NE,H] bf16
{
  __shared__ __align__(16) unsigned short bufrag[3072]; // A/o frags (swizzled)
  __shared__ __align__(8)  unsigned short qkvs[9792];   // 3 x 48 x 68
  __shared__ float biasf[4][64];
  __shared__ int idxs[48];

  const int tid = threadIdx.x;
  const int lane = tid & 63;
  const int w = tid >> 6;
  const int c15 = lane & 15;
  const int hi4 = lane >> 4;
  const int cid = blockIdx.x >> 1;            // factor chunk
  const int sub = blockIdx.x & 1;             // slice-quad within half
  const int col = 16 * w + c15;
  const int swz = (c15 ^ (hi4 << 2));

  if (tid < 48) idxs[tid] = indices[cid * 48 + tid];
  if (tid < 64) {
    biasf[0][tid] = bq[tid];
    biasf[1][tid] = bk[tid];
    biasf[2][tid] = bv[tid];
    biasf[3][tid] = bo[tid];
  }

  s16x8 wB[3][2], wB3[2];
#pragma unroll
  for (int m = 0; m < 3; ++m) {
    const float* Wm = (m == 0) ? Wq : (m == 1) ? Wk : Wv;
#pragma unroll
    for (int ks = 0; ks < 2; ++ks) {
      union { s16x8 v; short s[8]; } u;
#pragma unroll
      for (int j = 0; j < 8; ++j)
        u.s[j] = (short)f2b(Wm[(ks * 32 + hi4 * 8 + j) * 64 + col]);
      wB[m][ks] = u.v;
    }
  }
#pragma unroll
  for (int ks = 0; ks < 2; ++ks) {
    union { s16x8 v; short s[8]; } u;
#pragma unroll
    for (int j = 0; j < 8; ++j)
      u.s[j] = (short)f2b(Wo[(ks * 32 + hi4 * 8 + j) * 64 + col]);
    wB3[ks] = u.v;
  }
  __syncthreads();

  u64 pf[3];
#pragma unroll
  for (int k = 0; k < 3; ++k) {
    int idx = k * 256 + tid, row = idx >> 4, g = idx & 15;
    pf[k] = *(const u64*)&hs[((size_t)(tb0 + sub * 4) * N_ + idxs[row]) * H_ + g * 4];
  }

  for (int it = 0; it < 4; ++it) {
    const int ls = sub * 4 + it;              // slice within half (0..7)
    __syncthreads();                          // B0
#pragma unroll
    for (int k = 0; k < 3; ++k) {
      int idx = k * 256 + tid, row = idx >> 4, g = idx & 15;
      int rt = row >> 4, cr = row & 15;
      int ks = g >> 3, h5 = (g >> 1) & 3, j = (g & 1) * 4;
      int cr2 = cr ^ (h5 << 2);
      *(u64*)&bufrag[((rt * 2 + ks) << 9) + ((h5 * 16 + cr2) << 3) + j] = pf[k];
    }
    __syncthreads();                          // B1

    s16x8 afr[3][2];
#pragma unroll
    for (int rt = 0; rt < 3; ++rt)
#pragma unroll
      for (int ks = 0; ks < 2; ++ks)
        afr[rt][ks] = *(const s16x8*)&bufrag[((rt * 2 + ks) << 9) + ((hi4 * 16 + swz) << 3)];
#pragma unroll
    for (int m = 0; m < 3; ++m) {
      float bias = biasf[m][col];
      float scl = (m == 0) ? 0.25f : 1.f;
#pragma unroll
      for (int rt = 0; rt < 3; ++rt) {
        f32x4 acc = (f32x4){0.f, 0.f, 0.f, 0.f};
        acc = __builtin_amdgcn_mfma_f32_16x16x32_bf16(afr[rt][0], wB[m][0], acc, 0, 0, 0);
        acc = __builtin_amdgcn_mfma_f32_16x16x32_bf16(afr[rt][1], wB[m][1], acc, 0, 0, 0);
#pragma unroll
        for (int r = 0; r < 4; ++r) {
          int row = 16 * rt + hi4 * 4 + r;
          qkvs[m * 3264 + row * 68 + col] = f2b((acc[r] + bias) * scl);
        }
      }
    }
    if (it < 3) {
      const size_t base = (size_t)(tb0 + ls + 1) * N_;
#pragma unroll
      for (int k = 0; k < 3; ++k) {
        int idx = k * 256 + tid, row = idx >> 4, g = idx & 15;
        pf[k] = *(const u64*)&hs[(base + idxs[row]) * H_ + g * 4];
      }
    }
    __syncthreads();                          // B2

    {
      int f = tid >> 4, head = (tid >> 2) & 3, dq = tid & 3;
      int colb = head * 16 + dq * 4;
      float qv[3][4], kv[3][4], vv[3][4];
#pragma unroll
      for (int qi = 0; qi < 3; ++qi) {
        int base = (3 * f + qi) * 68 + colb;
        u64 uq = *(const u64*)&qkvs[base];
        u64 uk = *(const u64*)&qkvs[3264 + base];
        u64 uv = *(const u64*)&qkvs[6528 + base];
#pragma unroll
        for (int e = 0; e < 4; ++e) {
          qv[qi][e] = b2f((unsigned short)(uq >> (16 * e)));
          kv[qi][e] = b2f((unsigned short)(uk >> (16 * e)));
          vv[qi][e] = b2f((unsigned short)(uv >> (16 * e)));
        }
      }
      float s[3][3];
#pragma unroll
      for (int qi = 0; qi < 3; ++qi)
#pragma unroll
        for (int ki = 0; ki < 3; ++ki) {
          float a = qv[qi][0] * kv[ki][0] + qv[qi][1] * kv[ki][1]
                  + qv[qi][2] * kv[ki][2] + qv[qi][3] * kv[ki][3];
          a += __shfl_xor(a, 1, 64);
          a += __shfl_xor(a, 2, 64);
          s[qi][ki] = a;
        }
      const int ks2 = colb >> 5, h5b = (colb >> 3) & 3, jb = colb & 7;
#pragma unroll
      for (int qi = 0; qi < 3; ++qi) {
        float mx = fmaxf(s[qi][0], fmaxf(s[qi][1], s[qi][2]));
        float e0 = __expf(s[qi][0] - mx), e1 = __expf(s[qi][1] - mx), e2 = __expf(s[qi][2] - mx);
        float inv = __fdividef(1.f, e0 + e1 + e2);
        e0 *= inv; e1 *= inv; e2 *= inv;
        int row = 3 * f + qi;
        int rt = row >> 4, cr2 = (row & 15) ^ (h5b << 2);
        u64 pack = 0;
#pragma unroll
        for (int e = 0; e < 4; ++e) {
          float o = e0 * vv[0][e] + e1 * vv[1][e] + e2 * vv[2][e];
          pack |= (u64)f2b(o) << (16 * e);
        }
        *(u64*)&bufrag[((rt * 2 + ks2) << 9) + ((h5b * 16 + cr2) << 3) + jb] = pack;
      }
    }
    __syncthreads();                          // B3

    {
      const float bo_ = biasf[3][col];
      const size_t abase = (size_t)ls * NE_ + (size_t)cid * 48;
#pragma unroll
      for (int rt = 0; rt < 3; ++rt) {
        s16x8 o0 = *(const s16x8*)&bufrag[((rt * 2 + 0) << 9) + ((hi4 * 16 + swz) << 3)];
        s16x8 o1 = *(const s16x8*)&bufrag[((rt * 2 + 1) << 9) + ((hi4 * 16 + swz) << 3)];
        f32x4 acc = (f32x4){0.f, 0.f, 0.f, 0.f};
        acc = __builtin_amdgcn_mfma_f32_16x16x32_bf16(o0, wB3[0], acc, 0, 0, 0);
        acc = __builtin_amdgcn_mfma_f32_16x16x32_bf16(o1, wB3[1], acc, 0, 0, 0);
#pragma unroll
        for (int r = 0; r < 4; ++r) {
          int row = 16 * rt + hi4 * 4 + r;
          a_edge[(abase + row) * H_ + col] = f2b(acc[r] + bo_);
        }
      }
    }
  }
}

// ---------------------------------------------------------------------------
// Kernel 3: per-node CSR gather + logit MLP (w1T/arow bank-swizzled).
// ---------------------------------------------------------------------------
__global__ __launch_bounds__(256) void k_head(
    const int tb0,
    const unsigned short* __restrict__ a_edge, // [8,NE,H] bf16
    const int* __restrict__ offs, const int* __restrict__ elist,
    const float* __restrict__ nnz,
    const float* __restrict__ extra,
    const float* __restrict__ W1, const float* __restrict__ b1,
    const float* __restrict__ W2, const float* __restrict__ b2,
    float* __restrict__ yg,
    float* __restrict__ logit)
{
  __shared__ short w1T[64 * STR];
  __shared__ short arow[64 * STR];
  __shared__ float hEx[64];
  __shared__ float w2s[64];
  __shared__ float red[4][64];

  const int tid = threadIdx.x;
  const int lane = tid & 63;
  const int w = tid >> 6;
  const int c15 = lane & 15;
  const int hi4 = lane >> 4;
  const int bid = blockIdx.x;
  const int ls = bid >> 8;
  const int tb = tb0 + ls;
  const int nbase = (bid & 255) * 64;
  const int kall = nbase >> 12;

  for (int i = tid; i < 4096; i += 256) {
    int k = i >> 6, colc = i & 63;
    w1T[colc * STR + SWZ(colc, k)] = (short)f2b(W1[i]);
  }
  if (tid < 64) {
    float s = b1[tid];
#pragma unroll
    for (int e = 0; e < 4; ++e)
      s += extra[(tb * KALL_ + kall) * DE_ + e] * W1[(64 + e) * 64 + tid];
    hEx[tid] = s;
    w2s[tid] = W2[tid];
  }
  const size_t ebase = (size_t)ls * NE_;
  float accp = 0.f;
  for (int i = tid; i < 4096; i += 256) {
    int r = i >> 6, hcol = i & 63;
    int node = nbase + r;
    int beg = offs[node], end = offs[node + 1];
    float val = 0.f;
    for (int e = beg; e < end; ++e)
      val += b2f(a_edge[(ebase + elist[e]) * H_ + hcol]);
    val = __fdividef(val, nnz[node]);
    accp += val;
    arow[r * STR + SWZ(r, hcol)] = (short)f2b(val);
  }
  red[w][lane] = accp;
  __syncthreads();

  f32x4 acc[4];
#pragma unroll
  for (int ct = 0; ct < 4; ++ct) acc[ct] = (f32x4){0.f, 0.f, 0.f, 0.f};
  const int rowA = 16 * w + c15;
#pragma unroll
  for (int ks = 0; ks < 2; ++ks) {
    int kb = ks * 32 + hi4 * 8;
    s16x8 af = *(const s16x8*)&arow[rowA * STR + SWZ(rowA, kb)];
#pragma unroll
    for (int ct = 0; ct < 4; ++ct) {
      const int colB = 16 * ct + c15;
      s16x8 bfr = *(const s16x8*)&w1T[colB * STR + SWZ(colB, kb)];
      acc[ct] = __builtin_amdgcn_mfma_f32_16x16x32_bf16(af, bfr, acc[ct], 0, 0, 0);
    }
  }
  const float b2v = b2[0];
#pragma unroll
  for (int r = 0; r < 4; ++r) {
    float s = 0.f;
#pragma unroll
    for (int ct = 0; ct < 4; ++ct) {
      int colc = 16 * ct + c15;
      s += fmaxf(acc[ct][r] + hEx[colc], 0.f) * w2s[colc];
    }
    s += __shfl_xor(s, 1, 64);
    s += __shfl_xor(s, 2, 64);
    s += __shfl_xor(s, 4, 64);
    s += __shfl_xor(s, 8, 64);
    if (c15 == 0)
      logit[tb * N_ + nbase + 16 * w + hi4 * 4 + r] = s + b2v;
  }
  if (tid < 64) {
    float sv = red[0][tid] + red[1][tid] + red[2][tid] + red[3][tid];
    atomicAdd(&yg[(tb * KALL_ + kall) * H_ + tid], sv);
  }
}

// ---------------------------------------------------------------------------
// Kernel 4: value head + h_global passthrough
// ---------------------------------------------------------------------------
__global__ __launch_bounds__(256) void k_final(
    const float* __restrict__ yg,
    const float* __restrict__ extra,
    const float* __restrict__ Wv1, const float* __restrict__ bv1,
    const float* __restrict__ hg_in,
    float* __restrict__ value_out,
    float* __restrict__ hg_out)
{
  const int tid = threadIdx.x;
  if (tid < 16) {
    const float bv = bv1[0];
    float v = 0.f;
    for (int kall = 0; kall < 4; ++kall) {
      float s = bv;
      for (int hh = 0; hh < 64; ++hh)
        s += (yg[(tid * KALL_ + kall) * H_ + hh] * (1.f / 4096.f)) * Wv1[hh];
      for (int e = 0; e < 4; ++e)
        s += extra[(tid * KALL_ + kall) * DE_ + e] * Wv1[64 + e];
      v += s;
    }
    value_out[tid] = v;
  }
  for (int i = tid; i < 1024; i += 256) hg_out[i] = hg_in[i];
}

// ---------------------------------------------------------------------------
// Workspace layout (84.4 MB < 100.7 MB proven safe):
//   yg @0 | cnt @16384 | offs @81920 | cursor @147584 | elist @213120
//   hs @524288 (33.5 MB) | a_edge @34078720 (50.3 MB, reused per half)
// ---------------------------------------------------------------------------
extern "C" void kernel_launch(void* const* d_in, const int* in_sizes, int n_in,
                              void* d_out, int out_size, void* d_ws, size_t ws_size,
                              hipStream_t stream)
{
  (void)in_sizes; (void)n_in; (void)out_size; (void)ws_size;
  const float* h0    = (const float*)d_in[0];
  const float* hg    = (const float*)d_in[1];
  const float* x     = (const float*)d_in[2];
  const float* extra = (const float*)d_in[3];
  const int*   dn    = (const int*)d_in[4];
  const int*   idx   = (const int*)d_in[5];
  const float* nnz   = (const float*)d_in[6];
  const float* Wi    = (const float*)d_in[7];
  const float* bi    = (const float*)d_in[8];
  const float* Wh    = (const float*)d_in[9];
  const float* bhn   = (const float*)d_in[10];
  const float* Wq    = (const float*)d_in[11];
  const float* bq    = (const float*)d_in[12];
  const float* Wk    = (const float*)d_in[13];
  const float* bk    = (const float*)d_in[14];
  const float* Wv    = (const float*)d_in[15];
  const float* bv    = (const float*)d_in[16];
  const float* Wo    = (const float*)d_in[17];
  const float* bo    = (const float*)d_in[18];
  const float* W1    = (const float*)d_in[19];
  const float* b1    = (const float*)d_in[20];
  const float* W2    = (const float*)d_in[21];
  const float* b2    = (const float*)d_in[22];
  const float* Wv1   = (const float*)d_in[23];
  const float* bv1   = (const float*)d_in[24];

  float* out = (float*)d_out;
  float* out_hfin  = out;                 // [B,N,H]    4194304
  float* out_hg    = out + 4194304;       // [B,K,DOUT]    1024
  float* out_logit = out + 4195328;       // [T,B,N]     262144
  float* out_value = out + 4457472;       // [T,B]           16

  char* wsb = (char*)d_ws;
  float*          yg     = (float*)wsb;
  int*            cnt    = (int*)(wsb + 16384);
  int*            offs   = (int*)(wsb + 81920);
  int*            cursor = (int*)(wsb + 147584);
  int*            elist  = (int*)(wsb + 213120);
  unsigned short* hs     = (unsigned short*)(wsb + 524288);
  unsigned short* a_edge = (unsigned short*)(wsb + 34078720);

  hipMemsetAsync(wsb, 0, 81920, stream);      // yg + cnt
  k_csr_count<<<192, 256, 0, stream>>>(idx, cnt);
  k_csr_scan<<<1, 256, 0, stream>>>(cnt, offs, cursor);
  k_csr_fill<<<192, 256, 0, stream>>>(idx, cursor, elist);
  k_gru<<<1024, 256, 0, stream>>>(h0, x, dn, Wi, bi, Wh, bhn, hs, out_hfin);
  for (int half = 0; half < 2; ++half) {
    const int tb0 = half * 8;
    k_attn<<<2048, 256, 0, stream>>>(tb0, hs, idx, Wq, bq, Wk, bk, Wv, bv,
                                     Wo, bo, a_edge);
    k_head<<<2048, 256, 0, stream>>>(tb0, a_edge, offs, elist, nnz, extra,
                                     W1, b1, W2, b2, yg, out_logit);
  }
  k_final<<<1, 256, 0, stream>>>(yg, extra, Wv1, bv1, hg, out_value, out_hg);
}

// Round 11
// 383.244 us; speedup vs baseline: 1.0910x; 1.0910x over previous
//
#include <hip/hip_runtime.h>
#include <hip/hip_bf16.h>

#define T_ 4
#define B_ 4
#define N_ 16384
#define KALL_ 4
#define F_ 16384
#define ORD_ 3
#define DIN_ 4
#define H_ 64
#define H3_ 192
#define DE_ 4
#define STR 72     // padded bf16 leading-dim for MFMA A/B LDS tiles
#define NE_ 49152  // F*ORD edges

typedef __attribute__((ext_vector_type(8))) short s16x8;
typedef __attribute__((ext_vector_type(4))) float f32x4;
typedef unsigned long long u64;

static __device__ __forceinline__ float b2f(unsigned short u) {
  union { unsigned u; float f; } x; x.u = ((unsigned)u) << 16; return x.f;
}
static __device__ __forceinline__ unsigned short f2b(float f) {
  __hip_bfloat16 h = __float2bfloat16(f);  // RNE
  union { __hip_bfloat16 h; unsigned short u; } x; x.h = h; return x.u;
}
static __device__ __forceinline__ float fast_sigmoid(float v) {
  return __fdividef(1.f, 1.f + __expf(-v));
}
static __device__ __forceinline__ float fast_tanh(float v) {
  float e = __expf(2.f * v);
  return __fdividef(e - 1.f, e + 1.f);
}

// dones encoding sniffer (proven in R7-R10)
static __device__ __forceinline__ bool decode_done(const int* __restrict__ dn, int tb) {
  bool word = true;
#pragma unroll
  for (int i = 0; i < 16; ++i) {
    int v = dn[i];
    if (v != 0 && v != 1 && v != 0x3F800000) word = false;
  }
  if (word) return dn[tb] != 0;
  return ((const unsigned char*)dn)[tb] != 0;
}

// ---------------------------------------------------------------------------
// CSR build (unchanged)
// ---------------------------------------------------------------------------
__global__ __launch_bounds__(256) void k_csr_count(
    const int* __restrict__ idx, int* __restrict__ cnt) {
  int e = blockIdx.x * 256 + threadIdx.x;
  if (e < NE_) atomicAdd(&cnt[idx[e]], 1);
}
__global__ __launch_bounds__(256) void k_csr_scan(
    const int* __restrict__ cnt, int* __restrict__ offs, int* __restrict__ cursor) {
  __shared__ int part[256];
  __shared__ int base[256];
  int t = threadIdx.x;
  int s = 0;
  for (int j = 0; j < 64; ++j) s += cnt[t * 64 + j];
  part[t] = s;
  __syncthreads();
  if (t == 0) {
    int run = 0;
    for (int i = 0; i < 256; ++i) { base[i] = run; run += part[i]; }
  }
  __syncthreads();
  int run = base[t];
  for (int j = 0; j < 64; ++j) {
    offs[t * 64 + j] = run;
    cursor[t * 64 + j] = run;
    run += cnt[t * 64 + j];
  }
  if (t == 255) offs[N_] = run;
}
__global__ __launch_bounds__(256) void k_csr_fill(
    const int* __restrict__ idx, int* __restrict__ cursor, int* __restrict__ elist) {
  int e = blockIdx.x * 256 + threadIdx.x;
  if (e < NE_) {
    int pos = atomicAdd(&cursor[idx[e]], 1);
    elist[pos] = e;
  }
}

// ---------------------------------------------------------------------------
// Kernel 1: GRU v3. R9 structure (plain STR-72 layout, NO swizzle, NO
// min-wave bound) + bf16-only carry (37.9 KB LDS -> 4 blocks/CU at VGPR~120)
// + fast sigmoid/tanh + hoisted dones.
// ---------------------------------------------------------------------------
__global__ __launch_bounds__(256) void k_gru(
    const float* __restrict__ h0,
    const float* __restrict__ x,
    const int* __restrict__ dones,
    const float* __restrict__ Wi,
    const float* __restrict__ bi,
    const float* __restrict__ Wh,
    const float* __restrict__ bhn,
    unsigned short* __restrict__ hs,     // [T*B,N,H] bf16
    float* __restrict__ hfin)            // [B,N,H] f32
{
  __shared__ short whT[H3_ * STR];   // whT[c][k] = Wh[k][c] (B-operand)
  __shared__ short carry[H_ * STR];  // carry[r][k] bf16 (A-operand + state)
  __shared__ float xt[256];

  const int tid = threadIdx.x;
  const int lane = tid & 63;
  const int w = tid >> 6;
  const int c15 = lane & 15;
  const int hi4 = lane >> 4;
  const int bid = blockIdx.x;
  const int b = bid >> 8;
  const int nbase = (bid & 255) * 64;

  for (int i = tid; i < H_ * H3_; i += 256) {
    int k = i / H3_;
    int c = i - k * H3_;
    whT[c * STR + k] = (short)f2b(Wh[i]);
  }
  for (int i = tid; i < H_ * H_; i += 256) {
    int r = i >> 6, k = i & 63;
    carry[r * STR + k] = (short)f2b(h0[(b * N_ + nbase + r) * H_ + k]);
  }
  bool rst[T_];
#pragma unroll
  for (int t = 0; t < T_; ++t) rst[t] = decode_done(dones, t * B_ + b);

  float wir[3][4][4], bir[3][4], bhnr[4];
#pragma unroll
  for (int cg = 0; cg < 4; ++cg) {
    int hc = 16 * cg + c15;
    bhnr[cg] = bhn[hc];
#pragma unroll
    for (int g = 0; g < 3; ++g) {
      bir[g][cg] = bi[g * 64 + hc];
#pragma unroll
      for (int kk = 0; kk < 4; ++kk)
        wir[g][cg][kk] = Wi[kk * H3_ + g * 64 + hc];
    }
  }
  __syncthreads();

  for (int t = 0; t < T_; ++t) {
    xt[tid] = x[((t * B_ + b) * N_ + nbase + (tid >> 2)) * DIN_ + (tid & 3)];
    if (rst[t]) {
      for (int i = tid; i < H_ * STR; i += 256) carry[i] = 0;
    }
    __syncthreads();

    f32x4 acc[12];
#pragma unroll
    for (int ct = 0; ct < 12; ++ct) acc[ct] = (f32x4){0.f, 0.f, 0.f, 0.f};
    const int rowA = 16 * w + c15;
#pragma unroll
    for (int ks = 0; ks < 2; ++ks) {
      const int kb = ks * 32 + hi4 * 8;
      s16x8 af = *(const s16x8*)&carry[rowA * STR + kb];
#pragma unroll
      for (int ct = 0; ct < 12; ++ct) {
        s16x8 bfr = *(const s16x8*)&whT[(16 * ct + c15) * STR + kb];
        acc[ct] = __builtin_amdgcn_mfma_f32_16x16x32_bf16(af, bfr, acc[ct], 0, 0, 0);
      }
    }
#pragma unroll
    for (int r = 0; r < 4; ++r) {
      const int row = 16 * w + hi4 * 4 + r;
      const int node = nbase + row;
      const float x0 = xt[row * 4 + 0], x1 = xt[row * 4 + 1],
                  x2 = xt[row * 4 + 2], x3 = xt[row * 4 + 3];
#pragma unroll
      for (int cg = 0; cg < 4; ++cg) {
        const int hc = 16 * cg + c15;
        float gr = bir[0][cg] + x0 * wir[0][cg][0] + x1 * wir[0][cg][1]
                 + x2 * wir[0][cg][2] + x3 * wir[0][cg][3] + acc[cg][r];
        float gz = bir[1][cg] + x0 * wir[1][cg][0] + x1 * wir[1][cg][1]
                 + x2 * wir[1][cg][2] + x3 * wir[1][cg][3] + acc[4 + cg][r];
        float gn = bir[2][cg] + x0 * wir[2][cg][0] + x1 * wir[2][cg][1]
                 + x2 * wir[2][cg][2] + x3 * wir[2][cg][3];
        float rg = fast_sigmoid(gr);
        float zg = fast_sigmoid(gz);
        float cold = b2f((unsigned short)carry[row * STR + hc]);
        float ng = fast_tanh(gn + rg * (acc[8 + cg][r] + bhnr[cg]));
        float nc = (1.f - zg) * ng + zg * cold;
        hs[((t * B_ + b) * N_ + node) * H_ + hc] = f2b(nc);
        if (t == T_ - 1) hfin[(b * N_ + node) * H_ + hc] = nc;
        carry[row * STR + hc] = (short)f2b(nc);
      }
    }
    __syncthreads();
  }
}

// ---------------------------------------------------------------------------
// Kernel 2: fused factor attention — exact R9 version (grid 1024, 8 slices
// per block, no atomics, swizzled frag LDS that measured clean in R9).
// ---------------------------------------------------------------------------
__global__ __launch_bounds__(256, 3) void k_attn(
    const int tb0,
    const unsigned short* __restrict__ hs,    // [T*B,N,H] bf16
    const int* __restrict__ indices,
    const float* __restrict__ Wq, const float* __restrict__ bq,
    const float* __restrict__ Wk, const float* __restrict__ bk,
    const float* __restrict__ Wv, const float* __restrict__ bv,
    const float* __restrict__ Wo, const float* __restrict__ bo,
    unsigned short* __restrict__ a_edge)      // [8,NE,H] bf16
{
  __shared__ __align__(16) unsigned short bufrag[3072];
  __shared__ __align__(8)  unsigned short qkvs[9792];
  __shared__ float biasf[4][64];
  __shared__ int idxs[48];

  const int tid = threadIdx.x;
  const int lane = tid & 63;
  const int w = tid >> 6;
  const int c15 = lane & 15;
  const int hi4 = lane >> 4;
  const int bid = blockIdx.x;
  const int col = 16 * w + c15;
  const int swz = (c15 ^ (hi4 << 2));

  if (tid < 48) idxs[tid] = indices[bid * 48 + tid];
  if (tid < 64) {
    biasf[0][tid] = bq[tid];
    biasf[1][tid] = bk[tid];
    biasf[2][tid] = bv[tid];
    biasf[3][tid] = bo[tid];
  }

  s16x8 wB[3][2], wB3[2];
#pragma unroll
  for (int m = 0; m < 3; ++m) {
    const float* Wm = (m == 0) ? Wq : (m == 1) ? Wk : Wv;
#pragma unroll
    for (int ks = 0; ks < 2; ++ks) {
      union { s16x8 v; short s[8]; } u;
#pragma unroll
      for (int j = 0; j < 8; ++j)
        u.s[j] = (short)f2b(Wm[(ks * 32 + hi4 * 8 + j) * 64 + col]);
      wB[m][ks] = u.v;
    }
  }
#pragma unroll
  for (int ks = 0; ks < 2; ++ks) {
    union { s16x8 v; short s[8]; } u;
#pragma unroll
    for (int j = 0; j < 8; ++j)
      u.s[j] = (short)f2b(Wo[(ks * 32 + hi4 * 8 + j) * 64 + col]);
    wB3[ks] = u.v;
  }
  __syncthreads();

  u64 pf[3];
#pragma unroll
  for (int k = 0; k < 3; ++k) {
    int idx = k * 256 + tid, row = idx >> 4, g = idx & 15;
    pf[k] = *(const u64*)&hs[((size_t)tb0 * N_ + idxs[row]) * H_ + g * 4];
  }

  for (int it = 0; it < 8; ++it) {
    __syncthreads();                          // B0
#pragma unroll
    for (int k = 0; k < 3; ++k) {
      int idx = k * 256 + tid, row = idx >> 4, g = idx & 15;
      int rt = row >> 4, cr = row & 15;
      int ks = g >> 3, h5 = (g >> 1) & 3, j = (g & 1) * 4;
      int cr2 = cr ^ (h5 << 2);
      *(u64*)&bufrag[((rt * 2 + ks) << 9) + ((h5 * 16 + cr2) << 3) + j] = pf[k];
    }
    __syncthreads();                          // B1

    s16x8 afr[3][2];
#pragma unroll
    for (int rt = 0; rt < 3; ++rt)
#pragma unroll
      for (int ks = 0; ks < 2; ++ks)
        afr[rt][ks] = *(const s16x8*)&bufrag[((rt * 2 + ks) << 9) + ((hi4 * 16 + swz) << 3)];
#pragma unroll
    for (int m = 0; m < 3; ++m) {
      float bias = biasf[m][col];
      float scl = (m == 0) ? 0.25f : 1.f;
#pragma unroll
      for (int rt = 0; rt < 3; ++rt) {
        f32x4 acc = (f32x4){0.f, 0.f, 0.f, 0.f};
        acc = __builtin_amdgcn_mfma_f32_16x16x32_bf16(afr[rt][0], wB[m][0], acc, 0, 0, 0);
        acc = __builtin_amdgcn_mfma_f32_16x16x32_bf16(afr[rt][1], wB[m][1], acc, 0, 0, 0);
#pragma unroll
        for (int r = 0; r < 4; ++r) {
          int row = 16 * rt + hi4 * 4 + r;
          qkvs[m * 3264 + row * 68 + col] = f2b((acc[r] + bias) * scl);
        }
      }
    }
    if (it < 7) {
      const size_t base = (size_t)(tb0 + it + 1) * N_;
#pragma unroll
      for (int k = 0; k < 3; ++k) {
        int idx = k * 256 + tid, row = idx >> 4, g = idx & 15;
        pf[k] = *(const u64*)&hs[(base + idxs[row]) * H_ + g * 4];
      }
    }
    __syncthreads();                          // B2

    {
      int f = tid >> 4, head = (tid >> 2) & 3, dq = tid & 3;
      int colb = head * 16 + dq * 4;
      float qv[3][4], kv[3][4], vv[3][4];
#pragma unroll
      for (int qi = 0; qi < 3; ++qi) {
        int base = (3 * f + qi) * 68 + colb;
        u64 uq = *(const u64*)&qkvs[base];
        u64 uk = *(const u64*)&qkvs[3264 + base];
        u64 uv = *(const u64*)&qkvs[6528 + base];
#pragma unroll
        for (int e = 0; e < 4; ++e) {
          qv[qi][e] = b2f((unsigned short)(uq >> (16 * e)));
          kv[qi][e] = b2f((unsigned short)(uk >> (16 * e)));
          vv[qi][e] = b2f((unsigned short)(uv >> (16 * e)));
        }
      }
      float s[3][3];
#pragma unroll
      for (int qi = 0; qi < 3; ++qi)
#pragma unroll
        for (int ki = 0; ki < 3; ++ki) {
          float a = qv[qi][0] * kv[ki][0] + qv[qi][1] * kv[ki][1]
                  + qv[qi][2] * kv[ki][2] + qv[qi][3] * kv[ki][3];
          a += __shfl_xor(a, 1, 64);
          a += __shfl_xor(a, 2, 64);
          s[qi][ki] = a;
        }
      const int ks2 = colb >> 5, h5b = (colb >> 3) & 3, jb = colb & 7;
#pragma unroll
      for (int qi = 0; qi < 3; ++qi) {
        float mx = fmaxf(s[qi][0], fmaxf(s[qi][1], s[qi][2]));
        float e0 = __expf(s[qi][0] - mx), e1 = __expf(s[qi][1] - mx), e2 = __expf(s[qi][2] - mx);
        float inv = __fdividef(1.f, e0 + e1 + e2);
        e0 *= inv; e1 *= inv; e2 *= inv;
        int row = 3 * f + qi;
        int rt = row >> 4, cr2 = (row & 15) ^ (h5b << 2);
        u64 pack = 0;
#pragma unroll
        for (int e = 0; e < 4; ++e) {
          float o = e0 * vv[0][e] + e1 * vv[1][e] + e2 * vv[2][e];
          pack |= (u64)f2b(o) << (16 * e);
        }
        *(u64*)&bufrag[((rt * 2 + ks2) << 9) + ((h5b * 16 + cr2) << 3) + jb] = pack;
      }
    }
    __syncthreads();                          // B3

    {
      const float bo_ = biasf[3][col];
      const size_t abase = (size_t)it * NE_ + (size_t)bid * 48;
#pragma unroll
      for (int rt = 0; rt < 3; ++rt) {
        s16x8 o0 = *(const s16x8*)&bufrag[((rt * 2 + 0) << 9) + ((hi4 * 16 + swz) << 3)];
        s16x8 o1 = *(const s16x8*)&bufrag[((rt * 2 + 1) << 9) + ((hi4 * 16 + swz) << 3)];
        f32x4 acc = (f32x4){0.f, 0.f, 0.f, 0.f};
        acc = __builtin_amdgcn_mfma_f32_16x16x32_bf16(o0, wB3[0], acc, 0, 0, 0);
        acc = __builtin_amdgcn_mfma_f32_16x16x32_bf16(o1, wB3[1], acc, 0, 0, 0);
#pragma unroll
        for (int r = 0; r < 4; ++r) {
          int row = 16 * rt + hi4 * 4 + r;
          a_edge[(abase + row) * H_ + col] = f2b(acc[r] + bo_);
        }
      }
    }
  }
}

// ---------------------------------------------------------------------------
// Kernel 3: per-node CSR gather + logit MLP — exact R9 version (no swizzle).
// ---------------------------------------------------------------------------
__global__ __launch_bounds__(256) void k_head(
    const int tb0,
    const unsigned short* __restrict__ a_edge, // [8,NE,H] bf16
    const int* __restrict__ offs, const int* __restrict__ elist,
    const float* __restrict__ nnz,
    const float* __restrict__ extra,
    const float* __restrict__ W1, const float* __restrict__ b1,
    const float* __restrict__ W2, const float* __restrict__ b2,
    float* __restrict__ yg,
    float* __restrict__ logit)
{
  __shared__ short w1T[64 * STR];
  __shared__ short arow[64 * STR];
  __shared__ float hEx[64];
  __shared__ float w2s[64];
  __shared__ float red[4][64];

  const int tid = threadIdx.x;
  const int lane = tid & 63;
  const int w = tid >> 6;
  const int c15 = lane & 15;
  const int hi4 = lane >> 4;
  const int bid = blockIdx.x;
  const int ls = bid >> 8;
  const int tb = tb0 + ls;
  const int nbase = (bid & 255) * 64;
  const int kall = nbase >> 12;

  for (int i = tid; i < 4096; i += 256) {
    int k = i >> 6, colc = i & 63;
    w1T[colc * STR + k] = (short)f2b(W1[i]);
  }
  if (tid < 64) {
    float s = b1[tid];
#pragma unroll
    for (int e = 0; e < 4; ++e)
      s += extra[(tb * KALL_ + kall) * DE_ + e] * W1[(64 + e) * 64 + tid];
    hEx[tid] = s;
    w2s[tid] = W2[tid];
  }
  const size_t ebase = (size_t)ls * NE_;
  float accp = 0.f;
  for (int i = tid; i < 4096; i += 256) {
    int r = i >> 6, hcol = i & 63;
    int node = nbase + r;
    int beg = offs[node], end = offs[node + 1];
    float val = 0.f;
    for (int e = beg; e < end; ++e)
      val += b2f(a_edge[(ebase + elist[e]) * H_ + hcol]);
    val = __fdividef(val, nnz[node]);
    accp += val;
    arow[r * STR + hcol] = (short)f2b(val);
  }
  red[w][lane] = accp;
  __syncthreads();

  f32x4 acc[4];
#pragma unroll
  for (int ct = 0; ct < 4; ++ct) acc[ct] = (f32x4){0.f, 0.f, 0.f, 0.f};
#pragma unroll
  for (int ks = 0; ks < 2; ++ks) {
    int kb = ks * 32 + hi4 * 8;
    s16x8 af = *(const s16x8*)&arow[(16 * w + c15) * STR + kb];
#pragma unroll
    for (int ct = 0; ct < 4; ++ct) {
      s16x8 bfr = *(const s16x8*)&w1T[(16 * ct + c15) * STR + kb];
      acc[ct] = __builtin_amdgcn_mfma_f32_16x16x32_bf16(af, bfr, acc[ct], 0, 0, 0);
    }
  }
  const float b2v = b2[0];
#pragma unroll
  for (int r = 0; r < 4; ++r) {
    float s = 0.f;
#pragma unroll
    for (int ct = 0; ct < 4; ++ct) {
      int colc = 16 * ct + c15;
      s += fmaxf(acc[ct][r] + hEx[colc], 0.f) * w2s[colc];
    }
    s += __shfl_xor(s, 1, 64);
    s += __shfl_xor(s, 2, 64);
    s += __shfl_xor(s, 4, 64);
    s += __shfl_xor(s, 8, 64);
    if (c15 == 0)
      logit[tb * N_ + nbase + 16 * w + hi4 * 4 + r] = s + b2v;
  }
  if (tid < 64) {
    float sv = red[0][tid] + red[1][tid] + red[2][tid] + red[3][tid];
    atomicAdd(&yg[(tb * KALL_ + kall) * H_ + tid], sv);
  }
}

// ---------------------------------------------------------------------------
// Kernel 4: value head + h_global passthrough
// ---------------------------------------------------------------------------
__global__ __launch_bounds__(256) void k_final(
    const float* __restrict__ yg,
    const float* __restrict__ extra,
    const float* __restrict__ Wv1, const float* __restrict__ bv1,
    const float* __restrict__ hg_in,
    float* __restrict__ value_out,
    float* __restrict__ hg_out)
{
  const int tid = threadIdx.x;
  if (tid < 16) {
    const float bv = bv1[0];
    float v = 0.f;
    for (int kall = 0; kall < 4; ++kall) {
      float s = bv;
      for (int hh = 0; hh < 64; ++hh)
        s += (yg[(tid * KALL_ + kall) * H_ + hh] * (1.f / 4096.f)) * Wv1[hh];
      for (int e = 0; e < 4; ++e)
        s += extra[(tid * KALL_ + kall) * DE_ + e] * Wv1[64 + e];
      v += s;
    }
    value_out[tid] = v;
  }
  for (int i = tid; i < 1024; i += 256) hg_out[i] = hg_in[i];
}

// ---------------------------------------------------------------------------
// Workspace layout (84.4 MB < 100.7 MB proven safe):
//   yg @0 | cnt @16384 | offs @81920 | cursor @147584 | elist @213120
//   hs @524288 (33.5 MB) | a_edge @34078720 (50.3 MB, reused per half)
// ---------------------------------------------------------------------------
extern "C" void kernel_launch(void* const* d_in, const int* in_sizes, int n_in,
                              void* d_out, int out_size, void* d_ws, size_t ws_size,
                              hipStream_t stream)
{
  (void)in_sizes; (void)n_in; (void)out_size; (void)ws_size;
  const float* h0    = (const float*)d_in[0];
  const float* hg    = (const float*)d_in[1];
  const float* x     = (const float*)d_in[2];
  const float* extra = (const float*)d_in[3];
  const int*   dn    = (const int*)d_in[4];
  const int*   idx   = (const int*)d_in[5];
  const float* nnz   = (const float*)d_in[6];
  const float* Wi    = (const float*)d_in[7];
  const float* bi    = (const float*)d_in[8];
  const float* Wh    = (const float*)d_in[9];
  const float* bhn   = (const float*)d_in[10];
  const float* Wq    = (const float*)d_in[11];
  const float* bq    = (const float*)d_in[12];
  const float* Wk    = (const float*)d_in[13];
  const float* bk    = (const float*)d_in[14];
  const float* Wv    = (const float*)d_in[15];
  const float* bv    = (const float*)d_in[16];
  const float* Wo    = (const float*)d_in[17];
  const float* bo    = (const float*)d_in[18];
  const float* W1    = (const float*)d_in[19];
  const float* b1    = (const float*)d_in[20];
  const float* W2    = (const float*)d_in[21];
  const float* b2    = (const float*)d_in[22];
  const float* Wv1   = (const float*)d_in[23];
  const float* bv1   = (const float*)d_in[24];

  float* out = (float*)d_out;
  float* out_hfin  = out;                 // [B,N,H]    4194304
  float* out_hg    = out + 4194304;       // [B,K,DOUT]    1024
  float* out_logit = out + 4195328;       // [T,B,N]     262144
  float* out_value = out + 4457472;       // [T,B]           16

  char* wsb = (char*)d_ws;
  float*          yg     = (float*)wsb;
  int*            cnt    = (int*)(wsb + 16384);
  int*            offs   = (int*)(wsb + 81920);
  int*            cursor = (int*)(wsb + 147584);
  int*            elist  = (int*)(wsb + 213120);
  unsigned short* hs     = (unsigned short*)(wsb + 524288);
  unsigned short* a_edge = (unsigned short*)(wsb + 34078720);

  hipMemsetAsync(wsb, 0, 81920, stream);      // yg + cnt
  k_csr_count<<<192, 256, 0, stream>>>(idx, cnt);
  k_csr_scan<<<1, 256, 0, stream>>>(cnt, offs, cursor);
  k_csr_fill<<<192, 256, 0, stream>>>(idx, cursor, elist);
  k_gru<<<1024, 256, 0, stream>>>(h0, x, dn, Wi, bi, Wh, bhn, hs, out_hfin);
  for (int half = 0; half < 2; ++half) {
    const int tb0 = half * 8;
    k_attn<<<1024, 256, 0, stream>>>(tb0, hs, idx, Wq, bq, Wk, bk, Wv, bv,
                                     Wo, bo, a_edge);
    k_head<<<2048, 256, 0, stream>>>(tb0, a_edge, offs, elist, nnz, extra,
                                     W1, b1, W2, b2, yg, out_logit);
  }
  k_final<<<1, 256, 0, stream>>>(yg, extra, Wv1, bv1, hg, out_value, out_hg);
}

// Round 12
// 381.964 us; speedup vs baseline: 1.0947x; 1.0033x over previous
//
#include <hip/hip_runtime.h>
#include <hip/hip_bf16.h>

#define T_ 4
#define B_ 4
#define N_ 16384
#define KALL_ 4
#define F_ 16384
#define ORD_ 3
#define DIN_ 4
#define H_ 64
#define H3_ 192
#define DE_ 4
#define STR 72     // padded bf16 leading-dim for MFMA A/B LDS tiles
#define NE_ 49152  // F*ORD edges

typedef __attribute__((ext_vector_type(8))) short s16x8;
typedef __attribute__((ext_vector_type(4))) float f32x4;
typedef unsigned long long u64;

static __device__ __forceinline__ float b2f(unsigned short u) {
  union { unsigned u; float f; } x; x.u = ((unsigned)u) << 16; return x.f;
}
static __device__ __forceinline__ unsigned short f2b(float f) {
  __hip_bfloat16 h = __float2bfloat16(f);  // RNE
  union { __hip_bfloat16 h; unsigned short u; } x; x.h = h; return x.u;
}
static __device__ __forceinline__ float fast_sigmoid(float v) {
  return __fdividef(1.f, 1.f + __expf(-v));
}
static __device__ __forceinline__ float fast_tanh(float v) {
  float e = __expf(2.f * v);
  return __fdividef(e - 1.f, e + 1.f);
}

// dones encoding sniffer (proven in R7-R11)
static __device__ __forceinline__ bool decode_done(const int* __restrict__ dn, int tb) {
  bool word = true;
#pragma unroll
  for (int i = 0; i < 16; ++i) {
    int v = dn[i];
    if (v != 0 && v != 1 && v != 0x3F800000) word = false;
  }
  if (word) return dn[tb] != 0;
  return ((const unsigned char*)dn)[tb] != 0;
}

// ---------------------------------------------------------------------------
// CSR build (unchanged)
// ---------------------------------------------------------------------------
__global__ __launch_bounds__(256) void k_csr_count(
    const int* __restrict__ idx, int* __restrict__ cnt) {
  int e = blockIdx.x * 256 + threadIdx.x;
  if (e < NE_) atomicAdd(&cnt[idx[e]], 1);
}
__global__ __launch_bounds__(256) void k_csr_scan(
    const int* __restrict__ cnt, int* __restrict__ offs, int* __restrict__ cursor) {
  __shared__ int part[256];
  __shared__ int base[256];
  int t = threadIdx.x;
  int s = 0;
  for (int j = 0; j < 64; ++j) s += cnt[t * 64 + j];
  part[t] = s;
  __syncthreads();
  if (t == 0) {
    int run = 0;
    for (int i = 0; i < 256; ++i) { base[i] = run; run += part[i]; }
  }
  __syncthreads();
  int run = base[t];
  for (int j = 0; j < 64; ++j) {
    offs[t * 64 + j] = run;
    cursor[t * 64 + j] = run;
    run += cnt[t * 64 + j];
  }
  if (t == 255) offs[N_] = run;
}
__global__ __launch_bounds__(256) void k_csr_fill(
    const int* __restrict__ idx, int* __restrict__ cursor, int* __restrict__ elist) {
  int e = blockIdx.x * 256 + threadIdx.x;
  if (e < NE_) {
    int pos = atomicAdd(&cursor[idx[e]], 1);
    elist[pos] = e;
  }
}

// ---------------------------------------------------------------------------
// Kernel 1: GRU v4 — WAVE-SYNCHRONOUS t-loop (no per-t __syncthreads).
// Wave w owns carry rows [16w,16w+16) and xt slots [64w,64w+64) exclusively:
// A-frag reads, epilogue writes, and resets all stay inside the wave, so the
// only block-wide barrier needed is after whT staging. wave_barrier() pins
// LDS write->read ordering for the cross-LANE (same-wave) handoffs.
// ---------------------------------------------------------------------------
__global__ __launch_bounds__(256) void k_gru(
    const float* __restrict__ h0,
    const float* __restrict__ x,
    const int* __restrict__ dones,
    const float* __restrict__ Wi,
    const float* __restrict__ bi,
    const float* __restrict__ Wh,
    const float* __restrict__ bhn,
    unsigned short* __restrict__ hs,     // [T*B,N,H] bf16
    float* __restrict__ hfin)            // [B,N,H] f32
{
  __shared__ short whT[H3_ * STR];   // whT[c][k] = Wh[k][c] (B-operand)
  __shared__ short carry[H_ * STR];  // carry[r][k] bf16 (A-operand + state)
  __shared__ float xt[256];

  const int tid = threadIdx.x;
  const int lane = tid & 63;
  const int w = tid >> 6;
  const int c15 = lane & 15;
  const int hi4 = lane >> 4;
  const int bid = blockIdx.x;
  const int b = bid >> 8;
  const int nbase = (bid & 255) * 64;

  for (int i = tid; i < H_ * H3_; i += 256) {
    int k = i / H3_;
    int c = i - k * H3_;
    whT[c * STR + k] = (short)f2b(Wh[i]);
  }
  for (int i = tid; i < H_ * H_; i += 256) {
    int r = i >> 6, k = i & 63;
    carry[r * STR + k] = (short)f2b(h0[(b * N_ + nbase + r) * H_ + k]);
  }
  bool rst[T_];
#pragma unroll
  for (int t = 0; t < T_; ++t) rst[t] = decode_done(dones, t * B_ + b);

  float wir[3][4][4], bir[3][4], bhnr[4];
#pragma unroll
  for (int cg = 0; cg < 4; ++cg) {
    int hc = 16 * cg + c15;
    bhnr[cg] = bhn[hc];
#pragma unroll
    for (int g = 0; g < 3; ++g) {
      bir[g][cg] = bi[g * 64 + hc];
#pragma unroll
      for (int kk = 0; kk < 4; ++kk)
        wir[g][cg][kk] = Wi[kk * H3_ + g * 64 + hc];
    }
  }
  __syncthreads();   // the ONLY block-wide barrier: whT + initial carry ready

  const int wrow0 = 16 * w;            // this wave's carry row base
  for (int t = 0; t < T_; ++t) {
    // xt slots [64w,64w+64) written and read by wave w only
    xt[tid] = x[((t * B_ + b) * N_ + nbase + (tid >> 2)) * DIN_ + (tid & 3)];
    if (rst[t]) {
      // zero this wave's own 16 carry rows
      for (int i = lane; i < 16 * STR; i += 64) carry[wrow0 * STR + i] = 0;
    }
    __builtin_amdgcn_wave_barrier();   // pin LDS writes before cross-lane reads

    f32x4 acc[12];
#pragma unroll
    for (int ct = 0; ct < 12; ++ct) acc[ct] = (f32x4){0.f, 0.f, 0.f, 0.f};
    const int rowA = wrow0 + c15;
#pragma unroll
    for (int ks = 0; ks < 2; ++ks) {
      const int kb = ks * 32 + hi4 * 8;
      s16x8 af = *(const s16x8*)&carry[rowA * STR + kb];
#pragma unroll
      for (int ct = 0; ct < 12; ++ct) {
        s16x8 bfr = *(const s16x8*)&whT[(16 * ct + c15) * STR + kb];
        acc[ct] = __builtin_amdgcn_mfma_f32_16x16x32_bf16(af, bfr, acc[ct], 0, 0, 0);
      }
    }
    __builtin_amdgcn_wave_barrier();   // A-frag reads done before epilogue writes
#pragma unroll
    for (int r = 0; r < 4; ++r) {
      const int row = wrow0 + hi4 * 4 + r;
      const int node = nbase + row;
      const float x0 = xt[row * 4 + 0], x1 = xt[row * 4 + 1],
                  x2 = xt[row * 4 + 2], x3 = xt[row * 4 + 3];
#pragma unroll
      for (int cg = 0; cg < 4; ++cg) {
        const int hc = 16 * cg + c15;
        float gr = bir[0][cg] + x0 * wir[0][cg][0] + x1 * wir[0][cg][1]
                 + x2 * wir[0][cg][2] + x3 * wir[0][cg][3] + acc[cg][r];
        float gz = bir[1][cg] + x0 * wir[1][cg][0] + x1 * wir[1][cg][1]
                 + x2 * wir[1][cg][2] + x3 * wir[1][cg][3] + acc[4 + cg][r];
        float gn = bir[2][cg] + x0 * wir[2][cg][0] + x1 * wir[2][cg][1]
                 + x2 * wir[2][cg][2] + x3 * wir[2][cg][3];
        float rg = fast_sigmoid(gr);
        float zg = fast_sigmoid(gz);
        float cold = b2f((unsigned short)carry[row * STR + hc]);
        float ng = fast_tanh(gn + rg * (acc[8 + cg][r] + bhnr[cg]));
        float nc = (1.f - zg) * ng + zg * cold;
        hs[((t * B_ + b) * N_ + node) * H_ + hc] = f2b(nc);
        if (t == T_ - 1) hfin[(b * N_ + node) * H_ + hc] = nc;
        carry[row * STR + hc] = (short)f2b(nc);
      }
    }
    __builtin_amdgcn_wave_barrier();   // epilogue writes before next-t reads
  }
}

// ---------------------------------------------------------------------------
// Kernel 2: fused factor attention — exact R9/R11 version (unchanged).
// ---------------------------------------------------------------------------
__global__ __launch_bounds__(256, 3) void k_attn(
    const int tb0,
    const unsigned short* __restrict__ hs,    // [T*B,N,H] bf16
    const int* __restrict__ indices,
    const float* __restrict__ Wq, const float* __restrict__ bq,
    const float* __restrict__ Wk, const float* __restrict__ bk,
    const float* __restrict__ Wv, const float* __restrict__ bv,
    const float* __restrict__ Wo, const float* __restrict__ bo,
    unsigned short* __restrict__ a_edge)      // [8,NE,H] bf16
{
  __shared__ __align__(16) unsigned short bufrag[3072];
  __shared__ __align__(8)  unsigned short qkvs[9792];
  __shared__ float biasf[4][64];
  __shared__ int idxs[48];

  const int tid = threadIdx.x;
  const int lane = tid & 63;
  const int w = tid >> 6;
  const int c15 = lane & 15;
  const int hi4 = lane >> 4;
  const int bid = blockIdx.x;
  const int col = 16 * w + c15;
  const int swz = (c15 ^ (hi4 << 2));

  if (tid < 48) idxs[tid] = indices[bid * 48 + tid];
  if (tid < 64) {
    biasf[0][tid] = bq[tid];
    biasf[1][tid] = bk[tid];
    biasf[2][tid] = bv[tid];
    biasf[3][tid] = bo[tid];
  }

  s16x8 wB[3][2], wB3[2];
#pragma unroll
  for (int m = 0; m < 3; ++m) {
    const float* Wm = (m == 0) ? Wq : (m == 1) ? Wk : Wv;
#pragma unroll
    for (int ks = 0; ks < 2; ++ks) {
      union { s16x8 v; short s[8]; } u;
#pragma unroll
      for (int j = 0; j < 8; ++j)
        u.s[j] = (short)f2b(Wm[(ks * 32 + hi4 * 8 + j) * 64 + col]);
      wB[m][ks] = u.v;
    }
  }
#pragma unroll
  for (int ks = 0; ks < 2; ++ks) {
    union { s16x8 v; short s[8]; } u;
#pragma unroll
    for (int j = 0; j < 8; ++j)
      u.s[j] = (short)f2b(Wo[(ks * 32 + hi4 * 8 + j) * 64 + col]);
    wB3[ks] = u.v;
  }
  __syncthreads();

  u64 pf[3];
#pragma unroll
  for (int k = 0; k < 3; ++k) {
    int idx = k * 256 + tid, row = idx >> 4, g = idx & 15;
    pf[k] = *(const u64*)&hs[((size_t)tb0 * N_ + idxs[row]) * H_ + g * 4];
  }

  for (int it = 0; it < 8; ++it) {
    __syncthreads();                          // B0
#pragma unroll
    for (int k = 0; k < 3; ++k) {
      int idx = k * 256 + tid, row = idx >> 4, g = idx & 15;
      int rt = row >> 4, cr = row & 15;
      int ks = g >> 3, h5 = (g >> 1) & 3, j = (g & 1) * 4;
      int cr2 = cr ^ (h5 << 2);
      *(u64*)&bufrag[((rt * 2 + ks) << 9) + ((h5 * 16 + cr2) << 3) + j] = pf[k];
    }
    __syncthreads();                          // B1

    s16x8 afr[3][2];
#pragma unroll
    for (int rt = 0; rt < 3; ++rt)
#pragma unroll
      for (int ks = 0; ks < 2; ++ks)
        afr[rt][ks] = *(const s16x8*)&bufrag[((rt * 2 + ks) << 9) + ((hi4 * 16 + swz) << 3)];
#pragma unroll
    for (int m = 0; m < 3; ++m) {
      float bias = biasf[m][col];
      float scl = (m == 0) ? 0.25f : 1.f;
#pragma unroll
      for (int rt = 0; rt < 3; ++rt) {
        f32x4 acc = (f32x4){0.f, 0.f, 0.f, 0.f};
        acc = __builtin_amdgcn_mfma_f32_16x16x32_bf16(afr[rt][0], wB[m][0], acc, 0, 0, 0);
        acc = __builtin_amdgcn_mfma_f32_16x16x32_bf16(afr[rt][1], wB[m][1], acc, 0, 0, 0);
#pragma unroll
        for (int r = 0; r < 4; ++r) {
          int row = 16 * rt + hi4 * 4 + r;
          qkvs[m * 3264 + row * 68 + col] = f2b((acc[r] + bias) * scl);
        }
      }
    }
    if (it < 7) {
      const size_t base = (size_t)(tb0 + it + 1) * N_;
#pragma unroll
      for (int k = 0; k < 3; ++k) {
        int idx = k * 256 + tid, row = idx >> 4, g = idx & 15;
        pf[k] = *(const u64*)&hs[(base + idxs[row]) * H_ + g * 4];
      }
    }
    __syncthreads();                          // B2

    {
      int f = tid >> 4, head = (tid >> 2) & 3, dq = tid & 3;
      int colb = head * 16 + dq * 4;
      float qv[3][4], kv[3][4], vv[3][4];
#pragma unroll
      for (int qi = 0; qi < 3; ++qi) {
        int base = (3 * f + qi) * 68 + colb;
        u64 uq = *(const u64*)&qkvs[base];
        u64 uk = *(const u64*)&qkvs[3264 + base];
        u64 uv = *(const u64*)&qkvs[6528 + base];
#pragma unroll
        for (int e = 0; e < 4; ++e) {
          qv[qi][e] = b2f((unsigned short)(uq >> (16 * e)));
          kv[qi][e] = b2f((unsigned short)(uk >> (16 * e)));
          vv[qi][e] = b2f((unsigned short)(uv >> (16 * e)));
        }
      }
      float s[3][3];
#pragma unroll
      for (int qi = 0; qi < 3; ++qi)
#pragma unroll
        for (int ki = 0; ki < 3; ++ki) {
          float a = qv[qi][0] * kv[ki][0] + qv[qi][1] * kv[ki][1]
                  + qv[qi][2] * kv[ki][2] + qv[qi][3] * kv[ki][3];
          a += __shfl_xor(a, 1, 64);
          a += __shfl_xor(a, 2, 64);
          s[qi][ki] = a;
        }
      const int ks2 = colb >> 5, h5b = (colb >> 3) & 3, jb = colb & 7;
#pragma unroll
      for (int qi = 0; qi < 3; ++qi) {
        float mx = fmaxf(s[qi][0], fmaxf(s[qi][1], s[qi][2]));
        float e0 = __expf(s[qi][0] - mx), e1 = __expf(s[qi][1] - mx), e2 = __expf(s[qi][2] - mx);
        float inv = __fdividef(1.f, e0 + e1 + e2);
        e0 *= inv; e1 *= inv; e2 *= inv;
        int row = 3 * f + qi;
        int rt = row >> 4, cr2 = (row & 15) ^ (h5b << 2);
        u64 pack = 0;
#pragma unroll
        for (int e = 0; e < 4; ++e) {
          float o = e0 * vv[0][e] + e1 * vv[1][e] + e2 * vv[2][e];
          pack |= (u64)f2b(o) << (16 * e);
        }
        *(u64*)&bufrag[((rt * 2 + ks2) << 9) + ((h5b * 16 + cr2) << 3) + jb] = pack;
      }
    }
    __syncthreads();                          // B3

    {
      const float bo_ = biasf[3][col];
      const size_t abase = (size_t)it * NE_ + (size_t)bid * 48;
#pragma unroll
      for (int rt = 0; rt < 3; ++rt) {
        s16x8 o0 = *(const s16x8*)&bufrag[((rt * 2 + 0) << 9) + ((hi4 * 16 + swz) << 3)];
        s16x8 o1 = *(const s16x8*)&bufrag[((rt * 2 + 1) << 9) + ((hi4 * 16 + swz) << 3)];
        f32x4 acc = (f32x4){0.f, 0.f, 0.f, 0.f};
        acc = __builtin_amdgcn_mfma_f32_16x16x32_bf16(o0, wB3[0], acc, 0, 0, 0);
        acc = __builtin_amdgcn_mfma_f32_16x16x32_bf16(o1, wB3[1], acc, 0, 0, 0);
#pragma unroll
        for (int r = 0; r < 4; ++r) {
          int row = 16 * rt + hi4 * 4 + r;
          a_edge[(abase + row) * H_ + col] = f2b(acc[r] + bo_);
        }
      }
    }
  }
}

// ---------------------------------------------------------------------------
// Kernel 3: per-node CSR gather + logit MLP — exact R9/R11 version.
// ---------------------------------------------------------------------------
__global__ __launch_bounds__(256) void k_head(
    const int tb0,
    const unsigned short* __restrict__ a_edge, // [8,NE,H] bf16
    const int* __restrict__ offs, const int* __restrict__ elist,
    const float* __restrict__ nnz,
    const float* __restrict__ extra,
    const float* __restrict__ W1, const float* __restrict__ b1,
    const float* __restrict__ W2, const float* __restrict__ b2,
    float* __restrict__ yg,
    float* __restrict__ logit)
{
  __shared__ short w1T[64 * STR];
  __shared__ short arow[64 * STR];
  __shared__ float hEx[64];
  __shared__ float w2s[64];
  __shared__ float red[4][64];

  const int tid = threadIdx.x;
  const int lane = tid & 63;
  const int w = tid >> 6;
  const int c15 = lane & 15;
  const int hi4 = lane >> 4;
  const int bid = blockIdx.x;
  const int ls = bid >> 8;
  const int tb = tb0 + ls;
  const int nbase = (bid & 255) * 64;
  const int kall = nbase >> 12;

  for (int i = tid; i < 4096; i += 256) {
    int k = i >> 6, colc = i & 63;
    w1T[colc * STR + k] = (short)f2b(W1[i]);
  }
  if (tid < 64) {
    float s = b1[tid];
#pragma unroll
    for (int e = 0; e < 4; ++e)
      s += extra[(tb * KALL_ + kall) * DE_ + e] * W1[(64 + e) * 64 + tid];
    hEx[tid] = s;
    w2s[tid] = W2[tid];
  }
  const size_t ebase = (size_t)ls * NE_;
  float accp = 0.f;
  for (int i = tid; i < 4096; i += 256) {
    int r = i >> 6, hcol = i & 63;
    int node = nbase + r;
    int beg = offs[node], end = offs[node + 1];
    float val = 0.f;
    for (int e = beg; e < end; ++e)
      val += b2f(a_edge[(ebase + elist[e]) * H_ + hcol]);
    val = __fdividef(val, nnz[node]);
    accp += val;
    arow[r * STR + hcol] = (short)f2b(val);
  }
  red[w][lane] = accp;
  __syncthreads();

  f32x4 acc[4];
#pragma unroll
  for (int ct = 0; ct < 4; ++ct) acc[ct] = (f32x4){0.f, 0.f, 0.f, 0.f};
#pragma unroll
  for (int ks = 0; ks < 2; ++ks) {
    int kb = ks * 32 + hi4 * 8;
    s16x8 af = *(const s16x8*)&arow[(16 * w + c15) * STR + kb];
#pragma unroll
    for (int ct = 0; ct < 4; ++ct) {
      s16x8 bfr = *(const s16x8*)&w1T[(16 * ct + c15) * STR + kb];
      acc[ct] = __builtin_amdgcn_mfma_f32_16x16x32_bf16(af, bfr, acc[ct], 0, 0, 0);
    }
  }
  const float b2v = b2[0];
#pragma unroll
  for (int r = 0; r < 4; ++r) {
    float s = 0.f;
#pragma unroll
    for (int ct = 0; ct < 4; ++ct) {
      int colc = 16 * ct + c15;
      s += fmaxf(acc[ct][r] + hEx[colc], 0.f) * w2s[colc];
    }
    s += __shfl_xor(s, 1, 64);
    s += __shfl_xor(s, 2, 64);
    s += __shfl_xor(s, 4, 64);
    s += __shfl_xor(s, 8, 64);
    if (c15 == 0)
      logit[tb * N_ + nbase + 16 * w + hi4 * 4 + r] = s + b2v;
  }
  if (tid < 64) {
    float sv = red[0][tid] + red[1][tid] + red[2][tid] + red[3][tid];
    atomicAdd(&yg[(tb * KALL_ + kall) * H_ + tid], sv);
  }
}

// ---------------------------------------------------------------------------
// Kernel 4: value head + h_global passthrough
// ---------------------------------------------------------------------------
__global__ __launch_bounds__(256) void k_final(
    const float* __restrict__ yg,
    const float* __restrict__ extra,
    const float* __restrict__ Wv1, const float* __restrict__ bv1,
    const float* __restrict__ hg_in,
    float* __restrict__ value_out,
    float* __restrict__ hg_out)
{
  const int tid = threadIdx.x;
  if (tid < 16) {
    const float bv = bv1[0];
    float v = 0.f;
    for (int kall = 0; kall < 4; ++kall) {
      float s = bv;
      for (int hh = 0; hh < 64; ++hh)
        s += (yg[(tid * KALL_ + kall) * H_ + hh] * (1.f / 4096.f)) * Wv1[hh];
      for (int e = 0; e < 4; ++e)
        s += extra[(tid * KALL_ + kall) * DE_ + e] * Wv1[64 + e];
      v += s;
    }
    value_out[tid] = v;
  }
  for (int i = tid; i < 1024; i += 256) hg_out[i] = hg_in[i];
}

// ---------------------------------------------------------------------------
// Workspace layout (84.4 MB < 100.7 MB proven safe):
//   yg @0 | cnt @16384 | offs @81920 | cursor @147584 | elist @213120
//   hs @524288 (33.5 MB) | a_edge @34078720 (50.3 MB, reused per half)
// ---------------------------------------------------------------------------
extern "C" void kernel_launch(void* const* d_in, const int* in_sizes, int n_in,
                              void* d_out, int out_size, void* d_ws, size_t ws_size,
                              hipStream_t stream)
{
  (void)in_sizes; (void)n_in; (void)out_size; (void)ws_size;
  const float* h0    = (const float*)d_in[0];
  const float* hg    = (const float*)d_in[1];
  const float* x     = (const float*)d_in[2];
  const float* extra = (const float*)d_in[3];
  const int*   dn    = (const int*)d_in[4];
  const int*   idx   = (const int*)d_in[5];
  const float* nnz   = (const float*)d_in[6];
  const float* Wi    = (const float*)d_in[7];
  const float* bi    = (const float*)d_in[8];
  const float* Wh    = (const float*)d_in[9];
  const float* bhn   = (const float*)d_in[10];
  const float* Wq    = (const float*)d_in[11];
  const float* bq    = (const float*)d_in[12];
  const float* Wk    = (const float*)d_in[13];
  const float* bk    = (const float*)d_in[14];
  const float* Wv    = (const float*)d_in[15];
  const float* bv    = (const float*)d_in[16];
  const float* Wo    = (const float*)d_in[17];
  const float* bo    = (const float*)d_in[18];
  const float* W1    = (const float*)d_in[19];
  const float* b1    = (const float*)d_in[20];
  const float* W2    = (const float*)d_in[21];
  const float* b2    = (const float*)d_in[22];
  const float* Wv1   = (const float*)d_in[23];
  const float* bv1   = (const float*)d_in[24];

  float* out = (float*)d_out;
  float* out_hfin  = out;                 // [B,N,H]    4194304
  float* out_hg    = out + 4194304;       // [B,K,DOUT]    1024
  float* out_logit = out + 4195328;       // [T,B,N]     262144
  float* out_value = out + 4457472;       // [T,B]           16

  char* wsb = (char*)d_ws;
  float*          yg     = (float*)wsb;
  int*            cnt    = (int*)(wsb + 16384);
  int*            offs   = (int*)(wsb + 81920);
  int*            cursor = (int*)(wsb + 147584);
  int*            elist  = (int*)(wsb + 213120);
  unsigned short* hs     = (unsigned short*)(wsb + 524288);
  unsigned short* a_edge = (unsigned short*)(wsb + 34078720);

  hipMemsetAsync(wsb, 0, 81920, stream);      // yg + cnt
  k_csr_count<<<192, 256, 0, stream>>>(idx, cnt);
  k_csr_scan<<<1, 256, 0, stream>>>(cnt, offs, cursor);
  k_csr_fill<<<192, 256, 0, stream>>>(idx, cursor, elist);
  k_gru<<<1024, 256, 0, stream>>>(h0, x, dn, Wi, bi, Wh, bhn, hs, out_hfin);
  for (int half = 0; half < 2; ++half) {
    const int tb0 = half * 8;
    k_attn<<<1024, 256, 0, stream>>>(tb0, hs, idx, Wq, bq, Wk, bk, Wv, bv,
                                     Wo, bo, a_edge);
    k_head<<<2048, 256, 0, stream>>>(tb0, a_edge, offs, elist, nnz, extra,
                                     W1, b1, W2, b2, yg, out_logit);
  }
  k_final<<<1, 256, 0, stream>>>(yg, extra, Wv1, bv1, hg, out_value, out_hg);
}